// Round 9
// baseline (926.123 us; speedup 1.0000x reference)
//
#include <hip/hip_runtime.h>

typedef unsigned short u16;
typedef unsigned int u32;

#define NB 16384
#define ND 1024
static constexpr size_t BD = (size_t)NB * ND;   // 16777216
static constexpr size_t DD = (size_t)ND * ND;   // 1048576

typedef __attribute__((ext_vector_type(8))) short s16x8;
typedef __attribute__((ext_vector_type(4))) float f32x4;

__device__ __forceinline__ u16 f2bf(float f) {
  union { float f; u32 u; } v; v.f = f;
  return (u16)((v.u + 0x7fffu + ((v.u >> 16) & 1u)) >> 16);  // RNE
}
__device__ __forceinline__ float asf(u32 u) {
  union { u32 u; float f; } v; v.u = u; return v.f;
}
__device__ __forceinline__ uint2 pack4(float a, float b, float c, float d) {
  uint2 p;
  p.x = (u32)f2bf(a) | ((u32)f2bf(b) << 16);
  p.y = (u32)f2bf(c) | ((u32)f2bf(d) << 16);
  return p;
}
__device__ __forceinline__ void load16bf(const u16* p, float* o) {
  const uint4* q = (const uint4*)p;
  uint4 u0 = q[0], u1 = q[1];
  u32 w[8] = {u0.x, u0.y, u0.z, u0.w, u1.x, u1.y, u1.z, u1.w};
#pragma unroll
  for (int i = 0; i < 8; ++i) {
    o[2 * i]     = asf(w[i] << 16);
    o[2 * i + 1] = asf(w[i] & 0xffff0000u);
  }
}

#define G2L(gp, lp) __builtin_amdgcn_global_load_lds( \
    (__attribute__((address_space(1))) void*)(void*)(gp), \
    (__attribute__((address_space(3))) void*)(lp), 16, 0, 0)

// ---------------------------------------------------------------------------
// 128x128 GEMM core (R5-proven, 912 TF): BK=64, 4 waves, 2 barriers/K-tile,
// 3 blocks/CU. Both-sides XOR swizzle (rule #21). R6-R8 verdict: 256^2 deep
// pipelines (coarse/4-phase/8-phase) all lose to this at K=1024 — inter-block
// TLP at 3 blocks/CU beats intra-block pipelining on this shape.
// ---------------------------------------------------------------------------
template<int BF16_OUT>
__device__ __forceinline__ void gemm_core(
    const u16* __restrict__ A, const u16* __restrict__ Bm,
    const float* __restrict__ bias, void* __restrict__ Cp,
    int N, int K, int ldc, int row0, int col0)
{
  __shared__ __align__(16) u16 lA[128 * 64];
  __shared__ __align__(16) u16 lB[128 * 64];
  const int tid  = threadIdx.x;
  const int wave = tid >> 6;
  const int lane = tid & 63;
  const int wm = (wave >> 1) * 64;
  const int wn = (wave & 1) * 64;
  const int fr = lane & 15;
  const int fq = lane >> 4;
  const int srow = tid >> 3;                       // 0..31
  const int scol = ((tid & 7) ^ (srow & 7)) * 8;   // inverse-swizzled source col

  f32x4 acc[4][4];
#pragma unroll
  for (int i = 0; i < 4; ++i)
#pragma unroll
    for (int j = 0; j < 4; ++j) acc[i][j] = (f32x4){0.f, 0.f, 0.f, 0.f};

  const u16* Abase = A  + (size_t)(row0 + srow) * K + scol;
  const u16* Bbase = Bm + (size_t)(col0 + srow) * K + scol;
  u16* lAw = lA + wave * 512;
  u16* lBw = lB + wave * 512;
  const int rsw = (fr & 7) << 3;

  for (int kt = 0; kt < K; kt += 64) {
#pragma unroll
    for (int c = 0; c < 4; ++c) {
      G2L(Abase + (size_t)(c * 32) * K + kt, lAw + c * 2048);
      G2L(Bbase + (size_t)(c * 32) * K + kt, lBw + c * 2048);
    }
    __syncthreads();

#pragma unroll
    for (int kk = 0; kk < 2; ++kk) {
      s16x8 af[4], bfr[4];
#pragma unroll
      for (int i = 0; i < 4; ++i) {
        af[i]  = *(const s16x8*)&lA[(wm + i * 16 + fr) * 64 + ((kk * 32 + fq * 8) ^ rsw)];
        bfr[i] = *(const s16x8*)&lB[(wn + i * 16 + fr) * 64 + ((kk * 32 + fq * 8) ^ rsw)];
      }
#pragma unroll
      for (int i = 0; i < 4; ++i)
#pragma unroll
        for (int j = 0; j < 4; ++j)
          acc[i][j] = __builtin_amdgcn_mfma_f32_16x16x32_bf16(af[i], bfr[j], acc[i][j], 0, 0, 0);
    }
    __syncthreads();
  }

#pragma unroll
  for (int i = 0; i < 4; ++i) {
#pragma unroll
    for (int j = 0; j < 4; ++j) {
      const int col = col0 + wn + j * 16 + fr;
      const float bb = bias ? bias[col] : 0.f;
#pragma unroll
      for (int r = 0; r < 4; ++r) {
        const int row = row0 + wm + i * 16 + fq * 4 + r;
        const float v = acc[i][j][r] + bb;
        if (BF16_OUT) ((u16*)Cp)[(size_t)row * ldc + col] = f2bf(v);
        else          ((float*)Cp)[(size_t)row * ldc + col] = v;
      }
    }
  }
}

__device__ __forceinline__ void swz_rowcol(int* row0, int* col0, int tile) {
  const int nwg = gridDim.x * gridDim.y;
  int wgid = blockIdx.y * gridDim.x + blockIdx.x;
  wgid = (wgid & 7) * (nwg >> 3) + (wgid >> 3);   // nwg divisible by 8 everywhere
  *row0 = (wgid / gridDim.x) * tile;
  *col0 = (wgid % gridDim.x) * tile;
}

template<int BF16_OUT>
__global__ __launch_bounds__(256, 3) void gemm_bt(
    const u16* __restrict__ A, const u16* __restrict__ Bm,
    const float* __restrict__ bias, void* __restrict__ Cp,
    int N, int K, int ldc)
{
  int row0, col0;
  swz_rowcol(&row0, &col0, 128);
  gemm_core<BF16_OUT>(A, Bm, bias, Cp, N, K, ldc, row0, col0);
}

struct Ptr3 { const u16* a0; const u16* a1; const u16* a2;
              u16* c0; u16* c1; u16* c2; };

// batched K-projection (V handled by av_gemm): kp_s = h_s @ Wk^T, N=1024.
// No bias (bk cancels in softmax exactly).
__global__ __launch_bounds__(256, 3) void kproj_gemm(
    Ptr3 p, const u16* __restrict__ Bm, int K)
{
  int row0, col0;
  swz_rowcol(&row0, &col0, 128);
  const u16* A; u16* C;
  if (blockIdx.z == 0)      { A = p.a0; C = p.c0; }
  else if (blockIdx.z == 1) { A = p.a1; C = p.c1; }
  else                      { A = p.a2; C = p.c2; }
  gemm_core<1>(A, Bm, nullptr, C, 1024, K, 1024, row0, col0);
}

// ---------------------------------------------------------------------------
// av_gemm: att = M @ Wv^T per head, where M[b,k] = sum_s w[b,h,s]*h_s[b,k].
// EXACT per-head algebra: the scalar head-weight commutes with the k-sum
// (R4's Wo-fold failed because Wo mixes heads; Wv does not). N-tile 128 ==
// one head, so h = col0>>7 is block-uniform and mixing weights live in regs.
// A-side: reg-staged blend (global plain cols -> f32 blend -> bf16 ->
// ds_write to the SAME swizzled LDS layout the compute reads). B-side:
// global_load_lds with pre-swizzled source, B = Wv rows (standard).
// ---------------------------------------------------------------------------
template<int S>
__global__ __launch_bounds__(256, 3) void av_gemm(
    const u16* __restrict__ hs0, const u16* __restrict__ hs1,
    const u16* __restrict__ hs2, const float* __restrict__ wmix,
    const u16* __restrict__ wv, u16* __restrict__ att)
{
  int row0, col0;
  swz_rowcol(&row0, &col0, 128);
  const int head = col0 >> 7;

  __shared__ __align__(16) u16 lA[128 * 64];
  __shared__ __align__(16) u16 lB[128 * 64];
  const int tid  = threadIdx.x;
  const int wave = tid >> 6;
  const int lane = tid & 63;
  const int wm = (wave >> 1) * 64;
  const int wn = (wave & 1) * 64;
  const int fr = lane & 15;
  const int fq = lane >> 4;
  const int srow = tid >> 3;                        // 0..31
  const int cg   = tid & 7;                         // plain col-group (A loads)
  const int scolB = (cg ^ (srow & 7)) * 8;          // pre-swizzled col (B G2L)
  const int rsw = (fr & 7) << 3;

  const u16* hsp[3] = {hs0, hs1, hs2};
  // per-chunk mixing weights (head fixed per block) — loaded once
  float wr[4][S];
#pragma unroll
  for (int c = 0; c < 4; ++c) {
    const int grow = row0 + c * 32 + srow;
#pragma unroll
    for (int s = 0; s < S; ++s)
      wr[c][s] = wmix[((size_t)grow * 8 + head) * S + s];
  }

  f32x4 acc[4][4];
#pragma unroll
  for (int i = 0; i < 4; ++i)
#pragma unroll
    for (int j = 0; j < 4; ++j) acc[i][j] = (f32x4){0.f, 0.f, 0.f, 0.f};

  const u16* Bbase = wv + (size_t)(col0 + srow) * ND + scolB;
  u16* lBw = lB + wave * 512;

  for (int kt = 0; kt < ND; kt += 64) {
#pragma unroll
    for (int c = 0; c < 4; ++c)
      G2L(Bbase + (size_t)(c * 32) * ND + kt, lBw + c * 2048);
    // A: blend-stage through registers (write-side swizzle)
#pragma unroll
    for (int c = 0; c < 4; ++c) {
      const int r = c * 32 + srow;
      const size_t goff = (size_t)(row0 + r) * ND + kt + cg * 8;
      float a8[8] = {0.f, 0.f, 0.f, 0.f, 0.f, 0.f, 0.f, 0.f};
#pragma unroll
      for (int s = 0; s < S; ++s) {
        uint4 u = *(const uint4*)(hsp[s] + goff);
        u32 wd[4] = {u.x, u.y, u.z, u.w};
        const float ws = wr[c][s];
#pragma unroll
        for (int i = 0; i < 4; ++i) {
          a8[2 * i]     += ws * asf(wd[i] << 16);
          a8[2 * i + 1] += ws * asf(wd[i] & 0xffff0000u);
        }
      }
      uint2 p0 = pack4(a8[0], a8[1], a8[2], a8[3]);
      uint2 p1 = pack4(a8[4], a8[5], a8[6], a8[7]);
      uint4 pv; pv.x = p0.x; pv.y = p0.y; pv.z = p1.x; pv.w = p1.y;
      *(uint4*)&lA[r * 64 + ((cg ^ (r & 7)) * 8)] = pv;   // r&7 == srow&7
    }
    __syncthreads();   // drains ds_writes (lgkm) + B G2L (vmcnt)

#pragma unroll
    for (int kk = 0; kk < 2; ++kk) {
      s16x8 af[4], bfr[4];
#pragma unroll
      for (int i = 0; i < 4; ++i) {
        af[i]  = *(const s16x8*)&lA[(wm + i * 16 + fr) * 64 + ((kk * 32 + fq * 8) ^ rsw)];
        bfr[i] = *(const s16x8*)&lB[(wn + i * 16 + fr) * 64 + ((kk * 32 + fq * 8) ^ rsw)];
      }
#pragma unroll
      for (int i = 0; i < 4; ++i)
#pragma unroll
        for (int j = 0; j < 4; ++j)
          acc[i][j] = __builtin_amdgcn_mfma_f32_16x16x32_bf16(af[i], bfr[j], acc[i][j], 0, 0, 0);
    }
    __syncthreads();
  }

#pragma unroll
  for (int i = 0; i < 4; ++i) {
#pragma unroll
    for (int j = 0; j < 4; ++j) {
      const int col = col0 + wn + j * 16 + fr;
#pragma unroll
      for (int r = 0; r < 4; ++r) {
        const int row = row0 + wm + i * 16 + fq * 4 + r;
        att[(size_t)row * ND + col] = f2bf(acc[i][j][r]);
      }
    }
  }
}

// ---------------------------------------------------------------------------
// prep: hier0 = f40+emb0 (f32 out + bf16), enh2/enh3 -> bf16
// ---------------------------------------------------------------------------
__global__ __launch_bounds__(256) void prep_k(
    const float* __restrict__ f40, const float* __restrict__ f200,
    const float* __restrict__ f400, const float* __restrict__ mag,
    float* __restrict__ out0, u16* __restrict__ h0b,
    u16* __restrict__ e2b, u16* __restrict__ e3b)
{
  const size_t j = ((size_t)blockIdx.x * 256 + threadIdx.x) * 4;
  const int d = (int)(j & 1023);
  float4 m0 = *(const float4*)(mag + d);
  float4 m2 = *(const float4*)(mag + 2 * ND + d);
  float4 m3 = *(const float4*)(mag + 3 * ND + d);
  float4 a  = *(const float4*)(f40 + j);
  float4 c2 = *(const float4*)(f200 + j);
  float4 c3 = *(const float4*)(f400 + j);
  float4 h0;
  h0.x = a.x + m0.x; h0.y = a.y + m0.y; h0.z = a.z + m0.z; h0.w = a.w + m0.w;
  *(float4*)(out0 + j) = h0;
  *(uint2*)(h0b + j) = pack4(h0.x, h0.y, h0.z, h0.w);
  *(uint2*)(e2b + j) = pack4(c2.x + m2.x, c2.y + m2.y, c2.z + m2.z, c2.w + m2.w);
  *(uint2*)(e3b + j) = pack4(c3.x + m3.x, c3.y + m3.y, c3.z + m3.z, c3.w + m3.w);
}

__global__ __launch_bounds__(256) void ones_k(float* __restrict__ p) {
  p[blockIdx.x * 256 + threadIdx.x] = 1.0f;
}

// convert in_w (3D*D) + out_w (D*D) to bf16 into wbf [wq | wk | wv | wo]
__global__ __launch_bounds__(256) void convw_k(
    const float* __restrict__ iw, const float* __restrict__ ow,
    u16* __restrict__ wbf)
{
  const size_t j = ((size_t)blockIdx.x * 256 + threadIdx.x) * 4;
  const size_t IW = (size_t)3 * ND * ND;
  const float* src = (j < IW) ? (iw + j) : (ow + (j - IW));
  float4 v = *(const float4*)src;
  *(uint2*)(wbf + j) = pack4(v.x, v.y, v.z, v.w);
}

// 1024x1024 f32 -> transposed bf16 (for Wvo GEMM B operand, level 0 only)
__global__ __launch_bounds__(256) void transpose_bf_k(
    const float* __restrict__ src, u16* __restrict__ dst)
{
  __shared__ float t[32][33];
  const int bx = blockIdx.x & 31, by = blockIdx.x >> 5;
  const int tx = threadIdx.x & 31, ty = threadIdx.x >> 5;   // ty 0..7
#pragma unroll
  for (int r = 0; r < 4; ++r)
    t[ty + r * 8][tx] = src[(size_t)(by * 32 + ty + r * 8) * ND + bx * 32 + tx];
  __syncthreads();
#pragma unroll
  for (int r = 0; r < 4; ++r)
    dst[(size_t)(bx * 32 + ty + r * 8) * ND + by * 32 + tx] = f2bf(t[tx][ty + r * 8]);
}

// c[i] = bo[i] + sum_k bv[k] * Wo[i,k]   (block per i)
__global__ __launch_bounds__(256) void biasfold_k(
    const float* __restrict__ bv, const float* __restrict__ wo,
    const float* __restrict__ bo, float* __restrict__ c0)
{
  const int i = blockIdx.x;
  float s = 0.f;
  for (int k = threadIdx.x; k < ND; k += 256) s += bv[k] * wo[(size_t)i * ND + k];
#pragma unroll
  for (int m = 1; m <= 32; m <<= 1) s += __shfl_xor(s, m, 64);
  __shared__ float red[4];
  const int wv = threadIdx.x >> 6, ln = threadIdx.x & 63;
  if (ln == 0) red[wv] = s;
  __syncthreads();
  if (threadIdx.x == 0) c0[i] = bo[i] + red[0] + red[1] + red[2] + red[3];
}

// ---------------------------------------------------------------------------
// score_k: per row b, per head: dots qp . kp_s, softmax -> mixing weights
// w[b,h,s] (f32) + head-averaged attn map. Wave per b; 8 lanes/head.
// kp streams are [B,1024] (K-only).
// ---------------------------------------------------------------------------
template<int S>
__global__ __launch_bounds__(256) void score_k(
    const u16* __restrict__ qp, const u16* __restrict__ k0,
    const u16* __restrict__ k1, const u16* __restrict__ k2,
    float* __restrict__ wout, float* __restrict__ amap)
{
  const int wave = threadIdx.x >> 6, lane = threadIdx.x & 63;
  const int b = blockIdx.x * 4 + wave;
  const int d0 = lane * 16;            // head = lane>>3
  const u16* kp[3] = {k0, k1, k2};

  float q[16];
  load16bf(qp + (size_t)b * ND + d0, q);

  float sc[S];
  float mx = -1e30f;
#pragma unroll
  for (int s = 0; s < S; ++s) {
    float k[16];
    load16bf(kp[s] + (size_t)b * ND + d0, k);
    float dot = 0.f;
#pragma unroll
    for (int i = 0; i < 16; ++i) dot += q[i] * k[i];
    dot += __shfl_xor(dot, 1, 64);
    dot += __shfl_xor(dot, 2, 64);
    dot += __shfl_xor(dot, 4, 64);
    sc[s] = dot * 0.08838834764831845f;   // 1/sqrt(128)
    mx = fmaxf(mx, sc[s]);
  }
  float w_[S];
  float den = 0.f;
#pragma unroll
  for (int s = 0; s < S; ++s) { w_[s] = __expf(sc[s] - mx); den += w_[s]; }
  const float inv = 1.f / den;

  const int h = lane >> 3;
#pragma unroll
  for (int s = 0; s < S; ++s) {
    const float wv_ = w_[s] * inv;       // identical across the head's 8 lanes
    if ((lane & 7) == 0) wout[((size_t)b * 8 + h) * S + s] = wv_;
    float t = wv_;
    t += __shfl_xor(t, 8, 64);
    t += __shfl_xor(t, 16, 64);
    t += __shfl_xor(t, 32, 64);
    if (lane == 0) amap[(size_t)b * S + s] = t * 0.125f;   // mean over 8 heads
  }
}

// ---------------------------------------------------------------------------
// LayerNorm: x = f + emb + obuf(bf16); writes f32 out + optional bf16 copy
// ---------------------------------------------------------------------------
__global__ __launch_bounds__(256) void ln_k(
    const float* __restrict__ f, const float* __restrict__ emb,
    const u16* __restrict__ ob, const float* __restrict__ lw,
    const float* __restrict__ lb, float* __restrict__ outp,
    u16* __restrict__ hbf)
{
  const int b = blockIdx.x, t = threadIdx.x;
  const int d = t * 4;
  const size_t off = (size_t)b * ND + d;
  float4 xf = *(const float4*)(f + off);
  float4 ef = *(const float4*)(emb + d);
  uint2 ov  = *(const uint2*)(ob + off);
  float o0 = asf(ov.x << 16), o1 = asf(ov.x & 0xffff0000u);
  float o2 = asf(ov.y << 16), o3 = asf(ov.y & 0xffff0000u);
  float x0 = xf.x + ef.x + o0;
  float x1 = xf.y + ef.y + o1;
  float x2 = xf.z + ef.z + o2;
  float x3 = xf.w + ef.w + o3;
  float s  = x0 + x1 + x2 + x3;
  float s2 = x0 * x0 + x1 * x1 + x2 * x2 + x3 * x3;
#pragma unroll
  for (int m = 1; m <= 32; m <<= 1) {
    s  += __shfl_xor(s,  m, 64);
    s2 += __shfl_xor(s2, m, 64);
  }
  __shared__ float red[8];
  const int wv = t >> 6, ln = t & 63;
  if (ln == 0) { red[wv] = s; red[4 + wv] = s2; }
  __syncthreads();
  s  = red[0] + red[1] + red[2] + red[3];
  s2 = red[4] + red[5] + red[6] + red[7];
  const float mean = s * (1.f / 1024.f);
  const float var  = s2 * (1.f / 1024.f) - mean * mean;
  const float r = rsqrtf(var + 1e-5f);
  float4 w4 = *(const float4*)(lw + d);
  float4 b4 = *(const float4*)(lb + d);
  float4 y;
  y.x = (x0 - mean) * r * w4.x + b4.x;
  y.y = (x1 - mean) * r * w4.y + b4.y;
  y.z = (x2 - mean) * r * w4.z + b4.z;
  y.w = (x3 - mean) * r * w4.w + b4.w;
  *(float4*)(outp + off) = y;
  if (hbf) *(uint2*)(hbf + off) = pack4(y.x, y.y, y.z, y.w);
}

// ---------------------------------------------------------------------------
extern "C" void kernel_launch(void* const* d_in, const int* in_sizes, int n_in,
                              void* d_out, int out_size, void* d_ws, size_t ws_size,
                              hipStream_t stream)
{
  const float* f40  = (const float*)d_in[0];
  const float* f100 = (const float*)d_in[1];
  const float* f200 = (const float*)d_in[2];
  const float* f400 = (const float*)d_in[3];
  const float* mag  = (const float*)d_in[4];
  const float* in_w[3]  = {(const float*)d_in[5],  (const float*)d_in[11], (const float*)d_in[17]};
  const float* in_b[3]  = {(const float*)d_in[6],  (const float*)d_in[12], (const float*)d_in[18]};
  const float* out_w[3] = {(const float*)d_in[7],  (const float*)d_in[13], (const float*)d_in[19]};
  const float* out_b[3] = {(const float*)d_in[8],  (const float*)d_in[14], (const float*)d_in[20]};
  const float* ln_w[3]  = {(const float*)d_in[9],  (const float*)d_in[15], (const float*)d_in[21]};
  const float* ln_b[3]  = {(const float*)d_in[10], (const float*)d_in[16], (const float*)d_in[22]};

  float* out = (float*)d_out;
  char* ws = (char*)d_ws;
  const size_t BF = BD * 2;          // bytes of one [B,D] bf16 buffer (32 MiB)
  u16* h0b  = (u16*)(ws);
  u16* h1b  = (u16*)(ws + BF);
  u16* h2b  = (u16*)(ws + 2 * BF);
  u16* qpb  = (u16*)(ws + 3 * BF);   // Q-proj out; also O-proj bf16 out (obuf)
  u16* attb = (u16*)(ws + 4 * BF);   // attended (av_gemm out); L0 wvT/wvo scratch
  u16* kv0  = (u16*)(ws + 5 * BF);   // kp stream 0 [B,1024]
  float* wmix = (float*)(ws + 6 * BF);   // mixing weights [B,8,3] f32 (1.5MB)
  u16* kv1  = (u16*)(ws + 7 * BF);   // kp stream 1; first BF doubles as enh2 bf16
  u16* kv2  = (u16*)(ws + 9 * BF);   // kp stream 2; first BF doubles as enh3 bf16
  u16* wbf  = (u16*)(ws + 11 * BF);  // 8 MiB per-level weights [wq|wk|wv|wo]
  float* cs = (float*)(ws + 11 * BF + 8 * (1ull << 20));  // 1024 f32 (O-bias)
  u16* e2b = kv1;
  u16* e3b = kv2;
  u16* hb[3] = {h0b, h1b, h2b};
  const float* f_lvl[3] = {f100, f200, f400};

  dim3 blk(256);
  prep_k<<<dim3((unsigned)(BD / 1024)), blk, 0, stream>>>(f40, f200, f400, mag, out, h0b, e2b, e3b);
  ones_k<<<dim3(NB / 256), blk, 0, stream>>>(out + 4 * BD);  // attn_map0 == 1 exactly (S=1)

  for (int l = 0; l < 3; ++l) {
    convw_k<<<dim3(4096), blk, 0, stream>>>(in_w[l], out_w[l], wbf);
    const u16* wq  = wbf;
    const u16* wk  = wbf + DD;        // Wk rows, N=1024
    const u16* wvB = wbf + 2 * DD;    // Wv rows
    const u16* wo  = wbf + 3 * DD;
    biasfold_k<<<dim3(1024), blk, 0, stream>>>(in_b[l] + 2 * ND, out_w[l], out_b[l], cs);

    if (l == 0) {
      // S=1: attn==1 for every head -> Wo-fold valid (head-uniform weights):
      // hier1 = LN(enh1 + h0 @ (Wo@Wv)^T + (Wo@bv + bo))
      u16* wvT = attb;             // scratch in attb (free until l=1 av)
      u16* wvo = attb + DD;
      transpose_bf_k<<<dim3(1024), blk, 0, stream>>>(in_w[0] + 2 * DD, wvT);
      gemm_bt<1><<<dim3(8, 8), blk, 0, stream>>>(wo, wvT, nullptr, wvo, ND, ND, ND);
      gemm_bt<1><<<dim3(8, 128), blk, 0, stream>>>(h0b, wvo, cs, qpb, ND, ND, ND);
    } else {
      const u16* eb = (l == 1) ? e2b : e3b;
      gemm_bt<1><<<dim3(8, 128), blk, 0, stream>>>(eb, wq, in_b[l], qpb, ND, ND, ND);
      Ptr3 p = {hb[0], hb[1], hb[2], kv0, kv1, kv2};
      kproj_gemm<<<dim3(8, 128, l + 1), blk, 0, stream>>>(p, wk, ND);
      if (l == 1) {
        score_k<2><<<dim3(NB / 4), blk, 0, stream>>>(qpb, kv0, kv1, kv2, wmix,
                                                     out + 4 * BD + NB);
        av_gemm<2><<<dim3(8, 128), blk, 0, stream>>>(h0b, h1b, h2b, wmix, wvB, attb);
      } else {
        score_k<3><<<dim3(NB / 4), blk, 0, stream>>>(qpb, kv0, kv1, kv2, wmix,
                                                     out + 4 * BD + 3 * NB);
        av_gemm<3><<<dim3(8, 128), blk, 0, stream>>>(h0b, h1b, h2b, wmix, wvB, attb);
      }
      gemm_bt<1><<<dim3(8, 128), blk, 0, stream>>>(attb, wo, cs, qpb, ND, ND, ND);
    }
    ln_k<<<dim3(NB), blk, 0, stream>>>(f_lvl[l], mag + (size_t)(l + 1) * ND, qpb,
                                       ln_w[l], ln_b[l], out + (size_t)(l + 1) * BD,
                                       (l < 2) ? hb[l + 1] : nullptr);
  }
}

// Round 11
// 856.103 us; speedup vs baseline: 1.0818x; 1.0818x over previous
//
#include <hip/hip_runtime.h>

typedef unsigned short u16;
typedef unsigned int u32;

#define NB 16384
#define ND 1024
static constexpr size_t BD = (size_t)NB * ND;   // 16777216
static constexpr size_t DD = (size_t)ND * ND;   // 1048576

typedef __attribute__((ext_vector_type(8))) short s16x8;
typedef __attribute__((ext_vector_type(4))) float f32x4;

__device__ __forceinline__ u16 f2bf(float f) {
  union { float f; u32 u; } v; v.f = f;
  return (u16)((v.u + 0x7fffu + ((v.u >> 16) & 1u)) >> 16);  // RNE
}
__device__ __forceinline__ float asf(u32 u) {
  union { u32 u; float f; } v; v.u = u; return v.f;
}
__device__ __forceinline__ uint2 pack4(float a, float b, float c, float d) {
  uint2 p;
  p.x = (u32)f2bf(a) | ((u32)f2bf(b) << 16);
  p.y = (u32)f2bf(c) | ((u32)f2bf(d) << 16);
  return p;
}
__device__ __forceinline__ void load16bf(const u16* p, float* o) {
  const uint4* q = (const uint4*)p;
  uint4 u0 = q[0], u1 = q[1];
  u32 w[8] = {u0.x, u0.y, u0.z, u0.w, u1.x, u1.y, u1.z, u1.w};
#pragma unroll
  for (int i = 0; i < 8; ++i) {
    o[2 * i]     = asf(w[i] << 16);
    o[2 * i + 1] = asf(w[i] & 0xffff0000u);
  }
}
__device__ __forceinline__ void store16bf(u16* p, const float* o) {
  uint4 u0, u1;
  u0.x = (u32)f2bf(o[0])  | ((u32)f2bf(o[1])  << 16);
  u0.y = (u32)f2bf(o[2])  | ((u32)f2bf(o[3])  << 16);
  u0.z = (u32)f2bf(o[4])  | ((u32)f2bf(o[5])  << 16);
  u0.w = (u32)f2bf(o[6])  | ((u32)f2bf(o[7])  << 16);
  u1.x = (u32)f2bf(o[8])  | ((u32)f2bf(o[9])  << 16);
  u1.y = (u32)f2bf(o[10]) | ((u32)f2bf(o[11]) << 16);
  u1.z = (u32)f2bf(o[12]) | ((u32)f2bf(o[13]) << 16);
  u1.w = (u32)f2bf(o[14]) | ((u32)f2bf(o[15]) << 16);
  ((uint4*)p)[0] = u0;
  ((uint4*)p)[1] = u1;
}

#define G2L(gp, lp) __builtin_amdgcn_global_load_lds( \
    (__attribute__((address_space(1))) void*)(void*)(gp), \
    (__attribute__((address_space(3))) void*)(lp), 16, 0, 0)

// ---------------------------------------------------------------------------
// 128x128 GEMM core (R5-proven, 912 TF = the m97-structure ceiling): BK=64,
// 4 waves, 2 barriers/K-tile, 3 blocks/CU. Both-sides XOR swizzle (rule #21).
// Session verdicts: 256^2 pipelines (coarse/4ph/8ph, R6-R8) all lose at
// K=1024 (inter-block TLP > intra-block pipelining on this shape); Wo-fold
// (R4) invalid for S>=2; blend-first mixed-V (R9) traffic/VALU-bound;
// Q-merge into the KV launch (R10) races with the e2b/e3b buffer overlay —
// Q MUST be a separate prior launch (stream ordering is the only thing
// sequencing the enh read before the kv overwrite).
// ---------------------------------------------------------------------------
template<int BF16_OUT>
__device__ __forceinline__ void gemm_core(
    const u16* __restrict__ A, const u16* __restrict__ Bm,
    const float* __restrict__ bias, void* __restrict__ Cp,
    int N, int K, int ldc, int row0, int col0)
{
  __shared__ __align__(16) u16 lA[128 * 64];
  __shared__ __align__(16) u16 lB[128 * 64];
  const int tid  = threadIdx.x;
  const int wave = tid >> 6;
  const int lane = tid & 63;
  const int wm = (wave >> 1) * 64;
  const int wn = (wave & 1) * 64;
  const int fr = lane & 15;
  const int fq = lane >> 4;
  const int srow = tid >> 3;                       // 0..31
  const int scol = ((tid & 7) ^ (srow & 7)) * 8;   // inverse-swizzled source col

  f32x4 acc[4][4];
#pragma unroll
  for (int i = 0; i < 4; ++i)
#pragma unroll
    for (int j = 0; j < 4; ++j) acc[i][j] = (f32x4){0.f, 0.f, 0.f, 0.f};

  const u16* Abase = A  + (size_t)(row0 + srow) * K + scol;
  const u16* Bbase = Bm + (size_t)(col0 + srow) * K + scol;
  u16* lAw = lA + wave * 512;
  u16* lBw = lB + wave * 512;
  const int rsw = (fr & 7) << 3;

  for (int kt = 0; kt < K; kt += 64) {
#pragma unroll
    for (int c = 0; c < 4; ++c) {
      G2L(Abase + (size_t)(c * 32) * K + kt, lAw + c * 2048);
      G2L(Bbase + (size_t)(c * 32) * K + kt, lBw + c * 2048);
    }
    __syncthreads();

#pragma unroll
    for (int kk = 0; kk < 2; ++kk) {
      s16x8 af[4], bfr[4];
#pragma unroll
      for (int i = 0; i < 4; ++i) {
        af[i]  = *(const s16x8*)&lA[(wm + i * 16 + fr) * 64 + ((kk * 32 + fq * 8) ^ rsw)];
        bfr[i] = *(const s16x8*)&lB[(wn + i * 16 + fr) * 64 + ((kk * 32 + fq * 8) ^ rsw)];
      }
#pragma unroll
      for (int i = 0; i < 4; ++i)
#pragma unroll
        for (int j = 0; j < 4; ++j)
          acc[i][j] = __builtin_amdgcn_mfma_f32_16x16x32_bf16(af[i], bfr[j], acc[i][j], 0, 0, 0);
    }
    __syncthreads();
  }

#pragma unroll
  for (int i = 0; i < 4; ++i) {
#pragma unroll
    for (int j = 0; j < 4; ++j) {
      const int col = col0 + wn + j * 16 + fr;
      const float bb = bias ? bias[col] : 0.f;
#pragma unroll
      for (int r = 0; r < 4; ++r) {
        const int row = row0 + wm + i * 16 + fq * 4 + r;
        const float v = acc[i][j][r] + bb;
        if (BF16_OUT) ((u16*)Cp)[(size_t)row * ldc + col] = f2bf(v);
        else          ((float*)Cp)[(size_t)row * ldc + col] = v;
      }
    }
  }
}

__device__ __forceinline__ void swz_rowcol(int* row0, int* col0, int tile) {
  const int nwg = gridDim.x * gridDim.y;
  int wgid = blockIdx.y * gridDim.x + blockIdx.x;
  wgid = (wgid & 7) * (nwg >> 3) + (wgid >> 3);   // nwg divisible by 8 everywhere
  *row0 = (wgid / gridDim.x) * tile;
  *col0 = (wgid % gridDim.x) * tile;
}

template<int BF16_OUT>
__global__ __launch_bounds__(256, 3) void gemm_bt(
    const u16* __restrict__ A, const u16* __restrict__ Bm,
    const float* __restrict__ bias, void* __restrict__ Cp,
    int N, int K, int ldc)
{
  int row0, col0;
  swz_rowcol(&row0, &col0, 128);
  gemm_core<BF16_OUT>(A, Bm, bias, Cp, N, K, ldc, row0, col0);
}

struct Ptr3 { const u16* a0; const u16* a1; const u16* a2;
              u16* c0; u16* c1; u16* c2; };

// batched KV projection: z = stream, shared weights, NO bias (bk cancels in
// softmax exactly; bv folded into O-bias c). N=2048 cols = [K | V].
// NOTE: must launch AFTER the Q projection (e2b/e3b alias kv1/kv2 halves).
__global__ __launch_bounds__(256, 3) void kv_gemm(
    Ptr3 p, const u16* __restrict__ Bm, int K)
{
  int row0, col0;
  swz_rowcol(&row0, &col0, 128);
  const u16* A; u16* C;
  if (blockIdx.z == 0)      { A = p.a0; C = p.c0; }
  else if (blockIdx.z == 1) { A = p.a1; C = p.c1; }
  else                      { A = p.a2; C = p.c2; }
  gemm_core<1>(A, Bm, nullptr, C, 2048, K, 2048, row0, col0);
}

// ---------------------------------------------------------------------------
// prep: hier0 = f40+emb0 (f32 out + bf16), enh2/enh3 -> bf16, amap0 = 1
// (grid = NB blocks, one per batch row)
// ---------------------------------------------------------------------------
__global__ __launch_bounds__(256) void prep_k(
    const float* __restrict__ f40, const float* __restrict__ f200,
    const float* __restrict__ f400, const float* __restrict__ mag,
    float* __restrict__ out0, u16* __restrict__ h0b,
    u16* __restrict__ e2b, u16* __restrict__ e3b, float* __restrict__ amap0)
{
  const size_t j = ((size_t)blockIdx.x * 256 + threadIdx.x) * 4;
  const int d = (int)(j & 1023);
  float4 m0 = *(const float4*)(mag + d);
  float4 m2 = *(const float4*)(mag + 2 * ND + d);
  float4 m3 = *(const float4*)(mag + 3 * ND + d);
  float4 a  = *(const float4*)(f40 + j);
  float4 c2 = *(const float4*)(f200 + j);
  float4 c3 = *(const float4*)(f400 + j);
  float4 h0;
  h0.x = a.x + m0.x; h0.y = a.y + m0.y; h0.z = a.z + m0.z; h0.w = a.w + m0.w;
  *(float4*)(out0 + j) = h0;
  *(uint2*)(h0b + j) = pack4(h0.x, h0.y, h0.z, h0.w);
  *(uint2*)(e2b + j) = pack4(c2.x + m2.x, c2.y + m2.y, c2.z + m2.z, c2.w + m2.w);
  *(uint2*)(e3b + j) = pack4(c3.x + m3.x, c3.y + m3.y, c3.z + m3.z, c3.w + m3.w);
  if (threadIdx.x == 0) amap0[blockIdx.x] = 1.0f;  // S=1 softmax == 1 exactly
}

// batched: all 3 levels' in_w (3D*D) + out_w (D*D) -> bf16 [wq|wk|wv|wo] x3
struct WPtrs { const float* iw0; const float* ow0;
               const float* iw1; const float* ow1;
               const float* iw2; const float* ow2; };
__global__ __launch_bounds__(256) void convw3_k(WPtrs wp, u16* __restrict__ wbf3)
{
  const int z = blockIdx.z;
  const float* iw = (z == 0) ? wp.iw0 : (z == 1) ? wp.iw1 : wp.iw2;
  const float* ow = (z == 0) ? wp.ow0 : (z == 1) ? wp.ow1 : wp.ow2;
  u16* dst = wbf3 + (size_t)z * 4 * DD;
  const size_t j = ((size_t)blockIdx.x * 256 + threadIdx.x) * 4;
  const size_t IW = 3 * DD;
  const float* src = (j < IW) ? (iw + j) : (ow + (j - IW));
  float4 v = *(const float4*)src;
  *(uint2*)(dst + j) = pack4(v.x, v.y, v.z, v.w);
}

// 1024x1024 f32 -> transposed bf16 (for Wvo GEMM B operand, level 0 only)
__global__ __launch_bounds__(256) void transpose_bf_k(
    const float* __restrict__ src, u16* __restrict__ dst)
{
  __shared__ float t[32][33];
  const int bx = blockIdx.x & 31, by = blockIdx.x >> 5;
  const int tx = threadIdx.x & 31, ty = threadIdx.x >> 5;   // ty 0..7
#pragma unroll
  for (int r = 0; r < 4; ++r)
    t[ty + r * 8][tx] = src[(size_t)(by * 32 + ty + r * 8) * ND + bx * 32 + tx];
  __syncthreads();
#pragma unroll
  for (int r = 0; r < 4; ++r)
    dst[(size_t)(bx * 32 + ty + r * 8) * ND + by * 32 + tx] = f2bf(t[tx][ty + r * 8]);
}

// batched O-bias fold, all levels: cs3[z][i] = bo_z[i] + sum_k bv_z[k]*Wo_z[i,k]
struct BPtrs { const float* bv0; const float* wo0; const float* bo0;
               const float* bv1; const float* wo1; const float* bo1;
               const float* bv2; const float* wo2; const float* bo2; };
__global__ __launch_bounds__(256) void biasfold3_k(BPtrs bp, float* __restrict__ cs3)
{
  const int z = blockIdx.z;
  const float* bv = (z == 0) ? bp.bv0 : (z == 1) ? bp.bv1 : bp.bv2;
  const float* wo = (z == 0) ? bp.wo0 : (z == 1) ? bp.wo1 : bp.wo2;
  const float* bo = (z == 0) ? bp.bo0 : (z == 1) ? bp.bo1 : bp.bo2;
  const int i = blockIdx.x;
  float s = 0.f;
  for (int k = threadIdx.x; k < ND; k += 256) s += bv[k] * wo[(size_t)i * ND + k];
#pragma unroll
  for (int m = 1; m <= 32; m <<= 1) s += __shfl_xor(s, m, 64);
  __shared__ float red[4];
  const int wv = threadIdx.x >> 6, ln = threadIdx.x & 63;
  if (ln == 0) red[wv] = s;
  __syncthreads();
  if (threadIdx.x == 0) cs3[(size_t)z * ND + i] = bo[i] + red[0] + red[1] + red[2] + red[3];
}

// ---------------------------------------------------------------------------
// attention core (per-head weights on V channels, pre-Wo): wave per row b;
// 8 lanes per head, 16 d-elems per lane. kv = [K | V], no biases.
// ---------------------------------------------------------------------------
template<int S>
__global__ __launch_bounds__(256) void attn_k(
    const u16* __restrict__ qp, const u16* __restrict__ kva,
    const u16* __restrict__ kvb, const u16* __restrict__ kvc,
    u16* __restrict__ att, float* __restrict__ amap)
{
  const int wave = threadIdx.x >> 6, lane = threadIdx.x & 63;
  const int b = blockIdx.x * 4 + wave;
  const int d0 = lane * 16;            // head = lane>>3
  const u16* kv[3] = {kva, kvb, kvc};

  float q[16];
  load16bf(qp + (size_t)b * ND + d0, q);

  float sc[S];
  float mx = -1e30f;
#pragma unroll
  for (int s = 0; s < S; ++s) {
    float k[16];
    load16bf(kv[s] + (size_t)b * 2 * ND + d0, k);
    float dot = 0.f;
#pragma unroll
    for (int i = 0; i < 16; ++i) dot += q[i] * k[i];
    dot += __shfl_xor(dot, 1, 64);
    dot += __shfl_xor(dot, 2, 64);
    dot += __shfl_xor(dot, 4, 64);
    sc[s] = dot * 0.08838834764831845f;   // 1/sqrt(128)
    mx = fmaxf(mx, sc[s]);
  }
  float w_[S];
  float den = 0.f;
#pragma unroll
  for (int s = 0; s < S; ++s) { w_[s] = __expf(sc[s] - mx); den += w_[s]; }
  const float inv = 1.f / den;

  float o[16] = {0.f, 0.f, 0.f, 0.f, 0.f, 0.f, 0.f, 0.f,
                 0.f, 0.f, 0.f, 0.f, 0.f, 0.f, 0.f, 0.f};
#pragma unroll
  for (int s = 0; s < S; ++s) {
    float v[16];
    load16bf(kv[s] + (size_t)b * 2 * ND + ND + d0, v);
    const float ws = w_[s] * inv;
#pragma unroll
    for (int i = 0; i < 16; ++i) o[i] += ws * v[i];
  }
  store16bf(att + (size_t)b * ND + d0, o);

#pragma unroll
  for (int s = 0; s < S; ++s) {
    float t = w_[s] * inv;      // identical across the 8 lanes of a head
    t += __shfl_xor(t, 8, 64);
    t += __shfl_xor(t, 16, 64);
    t += __shfl_xor(t, 32, 64);
    if (lane == 0) amap[(size_t)b * S + s] = t * 0.125f;  // mean over 8 heads
  }
}

// ---------------------------------------------------------------------------
// LayerNorm: x = f + emb + obuf(bf16); writes f32 out + optional bf16 copy
// ---------------------------------------------------------------------------
__global__ __launch_bounds__(256) void ln_k(
    const float* __restrict__ f, const float* __restrict__ emb,
    const u16* __restrict__ ob, const float* __restrict__ lw,
    const float* __restrict__ lb, float* __restrict__ outp,
    u16* __restrict__ hbf)
{
  const int b = blockIdx.x, t = threadIdx.x;
  const int d = t * 4;
  const size_t off = (size_t)b * ND + d;
  float4 xf = *(const float4*)(f + off);
  float4 ef = *(const float4*)(emb + d);
  uint2 ov  = *(const uint2*)(ob + off);
  float o0 = asf(ov.x << 16), o1 = asf(ov.x & 0xffff0000u);
  float o2 = asf(ov.y << 16), o3 = asf(ov.y & 0xffff0000u);
  float x0 = xf.x + ef.x + o0;
  float x1 = xf.y + ef.y + o1;
  float x2 = xf.z + ef.z + o2;
  float x3 = xf.w + ef.w + o3;
  float s  = x0 + x1 + x2 + x3;
  float s2 = x0 * x0 + x1 * x1 + x2 * x2 + x3 * x3;
#pragma unroll
  for (int m = 1; m <= 32; m <<= 1) {
    s  += __shfl_xor(s,  m, 64);
    s2 += __shfl_xor(s2, m, 64);
  }
  __shared__ float red[8];
  const int wv = t >> 6, ln = t & 63;
  if (ln == 0) { red[wv] = s; red[4 + wv] = s2; }
  __syncthreads();
  s  = red[0] + red[1] + red[2] + red[3];
  s2 = red[4] + red[5] + red[6] + red[7];
  const float mean = s * (1.f / 1024.f);
  const float var  = s2 * (1.f / 1024.f) - mean * mean;
  const float r = rsqrtf(var + 1e-5f);
  float4 w4 = *(const float4*)(lw + d);
  float4 b4 = *(const float4*)(lb + d);
  float4 y;
  y.x = (x0 - mean) * r * w4.x + b4.x;
  y.y = (x1 - mean) * r * w4.y + b4.y;
  y.z = (x2 - mean) * r * w4.z + b4.z;
  y.w = (x3 - mean) * r * w4.w + b4.w;
  *(float4*)(outp + off) = y;
  if (hbf) *(uint2*)(hbf + off) = pack4(y.x, y.y, y.z, y.w);
}

// ---------------------------------------------------------------------------
extern "C" void kernel_launch(void* const* d_in, const int* in_sizes, int n_in,
                              void* d_out, int out_size, void* d_ws, size_t ws_size,
                              hipStream_t stream)
{
  const float* f40  = (const float*)d_in[0];
  const float* f100 = (const float*)d_in[1];
  const float* f200 = (const float*)d_in[2];
  const float* f400 = (const float*)d_in[3];
  const float* mag  = (const float*)d_in[4];
  const float* in_w[3]  = {(const float*)d_in[5],  (const float*)d_in[11], (const float*)d_in[17]};
  const float* in_b[3]  = {(const float*)d_in[6],  (const float*)d_in[12], (const float*)d_in[18]};
  const float* out_w[3] = {(const float*)d_in[7],  (const float*)d_in[13], (const float*)d_in[19]};
  const float* out_b[3] = {(const float*)d_in[8],  (const float*)d_in[14], (const float*)d_in[20]};
  const float* ln_w[3]  = {(const float*)d_in[9],  (const float*)d_in[15], (const float*)d_in[21]};
  const float* ln_b[3]  = {(const float*)d_in[10], (const float*)d_in[16], (const float*)d_in[22]};

  float* out = (float*)d_out;
  char* ws = (char*)d_ws;
  const size_t BF = BD * 2;          // bytes of one [B,D] bf16 buffer (32 MiB)
  u16* h0b  = (u16*)(ws);
  u16* h1b  = (u16*)(ws + BF);
  u16* h2b  = (u16*)(ws + 2 * BF);
  u16* qpb  = (u16*)(ws + 3 * BF);   // Q-proj out; also O-proj bf16 out (obuf)
  u16* attb = (u16*)(ws + 4 * BF);   // attended; L0 wvT/wvo scratch
  u16* kv0  = (u16*)(ws + 5 * BF);   // [B,2048]
  u16* kv1  = (u16*)(ws + 7 * BF);   // first half doubles as enh2 bf16
  u16* kv2  = (u16*)(ws + 9 * BF);   // first half doubles as enh3 bf16
  u16* wbf3 = (u16*)(ws + 11 * BF);  // 24 MiB: per-level [wq|wk|wv|wo] x3
  float* cs3 = (float*)(ws + 11 * BF + 24 * (1ull << 20));  // 3x1024 f32 O-bias
  u16* e2b = kv1;
  u16* e3b = kv2;
  u16* hb[3] = {h0b, h1b, h2b};
  const float* f_lvl[3] = {f100, f200, f400};

  dim3 blk(256);

  // ---- upfront: activations prep + all weight prep ----
  prep_k<<<dim3(NB), blk, 0, stream>>>(f40, f200, f400, mag, out, h0b, e2b, e3b,
                                       out + 4 * BD);
  WPtrs wp = {in_w[0], out_w[0], in_w[1], out_w[1], in_w[2], out_w[2]};
  convw3_k<<<dim3(4096, 1, 3), blk, 0, stream>>>(wp, wbf3);
  BPtrs bp = {in_b[0] + 2 * ND, out_w[0], out_b[0],
              in_b[1] + 2 * ND, out_w[1], out_b[1],
              in_b[2] + 2 * ND, out_w[2], out_b[2]};
  biasfold3_k<<<dim3(1024, 1, 3), blk, 0, stream>>>(bp, cs3);
  // L0 Wvo prep: wvT/wvo scratch in attb (free until l=1 attn)
  u16* wvT = attb;
  u16* wvo = attb + DD;
  transpose_bf_k<<<dim3(1024), blk, 0, stream>>>(in_w[0] + 2 * DD, wvT);
  gemm_bt<1><<<dim3(8, 8), blk, 0, stream>>>(wbf3 + 3 * DD, wvT, nullptr, wvo,
                                             ND, ND, ND);

  // ---- level 0 (S=1: attn==1 for every head -> Wo-fold valid):
  //      hier1 = LN(enh1 + h0 @ (Wo@Wv)^T + (Wo@bv + bo)) ----
  gemm_bt<1><<<dim3(8, 128), blk, 0, stream>>>(h0b, wvo, cs3, qpb, ND, ND, ND);
  ln_k<<<dim3(NB), blk, 0, stream>>>(f100, mag + ND, qpb, ln_w[0], ln_b[0],
                                     out + BD, h1b);

  // ---- levels 1,2 ----
  for (int l = 1; l < 3; ++l) {
    const u16* wq  = wbf3 + (size_t)l * 4 * DD;
    const u16* wkv = wq + DD;          // [wk | wv] rows, N=2048
    const u16* wo  = wq + 3 * DD;
    const u16* eb  = (l == 1) ? e2b : e3b;
    // Q FIRST (separate launch): e2b/e3b alias kv1/kv2 halves — stream order
    // is what sequences this read before kv_gemm's overwrite (R10 lesson).
    gemm_bt<1><<<dim3(8, 128), blk, 0, stream>>>(eb, wq, in_b[l], qpb, ND, ND, ND);
    Ptr3 p = {hb[0], hb[1], hb[2], kv0, kv1, kv2};
    kv_gemm<<<dim3(16, 128, l + 1), blk, 0, stream>>>(p, wkv, ND);
    if (l == 1)
      attn_k<2><<<dim3(NB / 4), blk, 0, stream>>>(qpb, kv0, kv1, kv2, attb,
                                                  out + 4 * BD + NB);
    else
      attn_k<3><<<dim3(NB / 4), blk, 0, stream>>>(qpb, kv0, kv1, kv2, attb,
                                                  out + 4 * BD + 3 * NB);
    gemm_bt<1><<<dim3(8, 128), blk, 0, stream>>>(attb, wo, cs3 + (size_t)l * ND,
                                                 qpb, ND, ND, ND);
    ln_k<<<dim3(NB), blk, 0, stream>>>(f_lvl[l], mag + (size_t)(l + 1) * ND, qpb,
                                       ln_w[l], ln_b[l], out + (size_t)(l + 1) * BD,
                                       (l < 2) ? hb[l + 1] : nullptr);
  }
}